// Round 1
// baseline (11.517 us; speedup 1.0000x reference)
//
#include <hip/hip_runtime.h>

// MI upper bound (CLUB, non-variational), algebraically reduced:
//   upper_bound = (1/N) * sum_d S2_d - (1/N^2) * sum_d S1_d^2
// where S1_d = sum_i y[i,d], S2_d = sum_i y[i,d]^2.
// N=2048, D=64, input f32 row-major [N, D].

#define N_ROWS 2048
#define D_COLS 64
#define BLOCKS_A 64
#define THREADS_A 256
#define ROWS_PER_BLOCK (N_ROWS / BLOCKS_A)   // 32

__global__ __launch_bounds__(THREADS_A)
void mi_partial_sums(const float* __restrict__ y, float* __restrict__ ws) {
    __shared__ float s1s[THREADS_A];
    __shared__ float s2s[THREADS_A];
    const int t    = threadIdx.x;
    const int col  = t & 63;        // column this thread owns
    const int rsub = t >> 6;        // 0..3 row sub-group
    const int rowBase = blockIdx.x * ROWS_PER_BLOCK;

    float s1 = 0.0f, s2 = 0.0f;
    #pragma unroll
    for (int k = 0; k < ROWS_PER_BLOCK / 4; ++k) {   // 8 iterations
        const int row = rowBase + rsub + k * 4;
        const float v = y[row * D_COLS + col];       // coalesced: 256 consecutive floats / 256 threads
        s1 += v;
        s2 += v * v;
    }
    s1s[t] = s1;
    s2s[t] = s2;
    __syncthreads();

    if (t < 64) {
        const float a1 = s1s[t] + s1s[t + 64] + s1s[t + 128] + s1s[t + 192];
        const float a2 = s2s[t] + s2s[t + 64] + s2s[t + 128] + s2s[t + 192];
        ws[blockIdx.x * 128 + t]      = a1;   // per-column S1 partial
        ws[blockIdx.x * 128 + 64 + t] = a2;   // per-column S2 partial
    }
}

__global__ __launch_bounds__(64)
void mi_finalize(const float* __restrict__ ws, float* __restrict__ out) {
    const int d = threadIdx.x;  // 64 threads, one per column
    float S1 = 0.0f, S2 = 0.0f;
    #pragma unroll
    for (int b = 0; b < BLOCKS_A; ++b) {
        S1 += ws[b * 128 + d];
        S2 += ws[b * 128 + 64 + d];
    }
    const float invN = 1.0f / (float)N_ROWS;
    float v = S2 * invN - (S1 * invN) * (S1 * invN);

    // full-wave (64-lane) butterfly reduction
    #pragma unroll
    for (int off = 32; off > 0; off >>= 1)
        v += __shfl_down(v, off);

    if (d == 0) out[0] = v;
}

extern "C" void kernel_launch(void* const* d_in, const int* in_sizes, int n_in,
                              void* d_out, int out_size, void* d_ws, size_t ws_size,
                              hipStream_t stream) {
    const float* y = (const float*)d_in[0];
    float* out = (float*)d_out;
    float* ws  = (float*)d_ws;   // needs BLOCKS_A * 128 * 4 = 32 KB

    mi_partial_sums<<<BLOCKS_A, THREADS_A, 0, stream>>>(y, ws);
    mi_finalize<<<1, 64, 0, stream>>>(ws, out);
}

// Round 2
// 9.488 us; speedup vs baseline: 1.2138x; 1.2138x over previous
//
#include <hip/hip_runtime.h>

// MI upper bound (CLUB, non-variational), algebraically reduced:
//   upper_bound = (1/N) * sum_d S2_d - (1/N^2) * sum_d S1_d^2
// where S1_d = sum_i y[i,d], S2_d = sum_i y[i,d]^2.
// N=2048, D=64, input f32 row-major [N, D].
//
// Single fused kernel (1 graph node). Cross-block handoff via device-scope
// release/acquire atomics on 64-bit magic flags in d_ws; block 0 consumes.
// Flags are reset to 0 by the consumer each call -> deterministic replays.

#define N_ROWS 2048
#define D_COLS 64
#define NBLK 64
#define NTHR 256
#define ROWS_PER_BLOCK (N_ROWS / NBLK)   // 32
#define FLAG_MAGIC 0x5AC0FFEE0DDBA11ULL

// ws layout (floats):
//   [0 .. NBLK*128)      per-block partials: 64 S1 columns then 64 S2 columns
//   byte offset NBLK*128*4 = 32768: unsigned long long flags[NBLK]

__global__ __launch_bounds__(NTHR)
void mi_fused(const float* __restrict__ y, float* __restrict__ ws,
              float* __restrict__ out) {
    __shared__ float s1s[NTHR];
    __shared__ float s2s[NTHR];
    unsigned long long* flags = (unsigned long long*)(ws + NBLK * 128);

    const int t    = threadIdx.x;
    const int b    = blockIdx.x;
    const int col  = t & 63;        // column this thread owns
    const int rsub = t >> 6;        // 0..3 row sub-group
    const int rowBase = b * ROWS_PER_BLOCK;

    // ---- producer phase: per-block per-column partial sums ----
    float s1 = 0.0f, s2 = 0.0f;
    #pragma unroll
    for (int k = 0; k < ROWS_PER_BLOCK / 4; ++k) {   // 8 coalesced reads/thread
        const float v = y[(rowBase + rsub + 4 * k) * D_COLS + col];
        s1 += v;
        s2 += v * v;
    }
    s1s[t] = s1;
    s2s[t] = s2;
    __syncthreads();

    if (t < 64) {
        const float a1 = s1s[t] + s1s[t + 64] + s1s[t + 128] + s1s[t + 192];
        const float a2 = s2s[t] + s2s[t + 64] + s2s[t + 128] + s2s[t + 192];
        ws[b * 128 + t]      = a1;   // plain stores; wave 0 only
        ws[b * 128 + 64 + t] = a2;
    }
    // Release: lane 0 of wave 0 publishes. The partial stores above were
    // issued by the SAME wave, so the release store's vmcnt-drain + L2
    // writeback orders them to the device coherence point.
    if (t == 0)
        __hip_atomic_store(&flags[b], FLAG_MAGIC, __ATOMIC_RELEASE,
                           __HIP_MEMORY_SCOPE_AGENT);

    if (b != 0) return;

    // ---- consumer phase: block 0 only ----
    if (t < 64) {
        while (__hip_atomic_load(&flags[t], __ATOMIC_ACQUIRE,
                                 __HIP_MEMORY_SCOPE_AGENT) != FLAG_MAGIC) { }
        // reset for the next (deterministic) call
        __hip_atomic_store(&flags[t], 0ULL, __ATOMIC_RELAXED,
                           __HIP_MEMORY_SCOPE_AGENT);
    }
    __syncthreads();

    // Read partials with agent-scope loads (bypass possibly-stale caches).
    // 4 groups of 16 blocks each; thread t handles column t&63, group t>>6.
    const int grp = t >> 6;
    float S1 = 0.0f, S2 = 0.0f;
    #pragma unroll
    for (int k = 0; k < 16; ++k) {
        const int bb = grp * 16 + k;
        S1 += __hip_atomic_load(&ws[bb * 128 + col], __ATOMIC_RELAXED,
                                __HIP_MEMORY_SCOPE_AGENT);
        S2 += __hip_atomic_load(&ws[bb * 128 + 64 + col], __ATOMIC_RELAXED,
                                __HIP_MEMORY_SCOPE_AGENT);
    }
    s1s[t] = S1;
    s2s[t] = S2;
    __syncthreads();

    if (t < 64) {
        const float T1 = s1s[t] + s1s[t + 64] + s1s[t + 128] + s1s[t + 192];
        const float T2 = s2s[t] + s2s[t + 64] + s2s[t + 128] + s2s[t + 192];
        const float invN = 1.0f / (float)N_ROWS;
        float v = T2 * invN - (T1 * invN) * (T1 * invN);
        // full-wave (64-lane) butterfly reduction over columns
        #pragma unroll
        for (int off = 32; off > 0; off >>= 1)
            v += __shfl_down(v, off);
        if (t == 0) out[0] = v;
    }
}

extern "C" void kernel_launch(void* const* d_in, const int* in_sizes, int n_in,
                              void* d_out, int out_size, void* d_ws, size_t ws_size,
                              hipStream_t stream) {
    const float* y = (const float*)d_in[0];
    float* out = (float*)d_out;
    float* ws  = (float*)d_ws;   // needs NBLK*128*4 + NBLK*8 = 33280 B

    mi_fused<<<NBLK, NTHR, 0, stream>>>(y, ws, out);
}